// Round 5
// baseline (145.919 us; speedup 1.0000x reference)
//
#include <hip/hip_runtime.h>

#define IMH 512
#define IMW 512
#define TW 16
#define TH 8
#define HW_ (TW + 2)          // 18
#define HH_ (TH + 2)          // 10
#define NHALO (HW_ * HH_)     // 180
#define NPIX (TW * TH)        // 128 interior pixels per block
#define ROW 31                // padded floats per halo pixel (30 ch + 1 pad; gcd(31,32)=1)

typedef float f4 __attribute__((ext_vector_type(4)));
typedef float f4a __attribute__((ext_vector_type(4), aligned(4)));
typedef float f2a __attribute__((ext_vector_type(2), aligned(4)));

// Fused: stage A (pointwise Bayes update + sensitivity quotient rule) -> LDS,
// stage B (3x3 conv x 10 channel-groups + softmax + softmax-JVP) -> global.
// R5: break the 1-thread-per-pixel cap. 262K px = 4096 waves = only 16
// waves/CU grid-wide — the real reason occupancy averaged ~21% and every
// variant floored at ~40us (R3's LDS-residency bump was a no-op: the GRID,
// not LDS, was binding). Now 2 threads/px: half 0 = group-0 conv + softmax
// + JVP groups 1-4; half 1 recomputes group-0 conv/softmax (cheaper than a
// p-handoff barrier; +10% FMA, FMA is not the wall) + groups 5-9.
// Grid 2048 blocks = 8/CU, 6 resident (LDS 22,320B, VGPR cap 85 via
// launch_bounds(256,6)) -> 24 waves/CU (+50% latency hiding). Stage A,
// ROW=31 layout, and all read patterns unchanged. Halves are wave-uniform.
__global__ __launch_bounds__(256, 6)
void hmm_fused(const float* __restrict__ obs,
               const float* __restrict__ P,      // (S,O) indexed P[o*3+s] per einsum 'os,hwo->hws'
               const float* __restrict__ u_k,
               const float* __restrict__ w_k,    // (H,W,S,1,S,O) -> pix*27 + s*9 + i*3 + j
               const float* __restrict__ conv_w, // (S_out,S_in,3,3)
               const float* __restrict__ conv_b, // (S,)
               float* __restrict__ out) {        // [0, 512*512*3): u_kp1 ; rest: w_kp1_O
    __shared__ __align__(16) float lds[NHALO * ROW];   // 22,320 B -> 6-7 blocks/CU

    const int tid = threadIdx.x;
    const int w0 = blockIdx.x * TW;
    const int h0 = blockIdx.y * TH;

    // P into registers (wave-uniform -> SGPRs)
    float Pm[9];
#pragma unroll
    for (int i = 0; i < 9; ++i) Pm[i] = P[i];

    // ---------- Stage A: halo pixels -> Z (ch 0..2) and w_pre (ch 3..29) in LDS
    // 180 tasks over 256 threads: single round, waves 0-2 active.
    if (tid < NHALO) {
        const int p = tid;
        const int hh = h0 + p / HW_ - 1;
        const int ww = w0 + p % HW_ - 1;
        float* row = &lds[p * ROW];
        if (hh < 0 || hh >= IMH || ww < 0 || ww >= IMW) {
#pragma unroll
            for (int c = 0; c < 30; ++c) row[c] = 0.0f;   // SAME zero padding
        } else {
            const int pix = hh * IMW + ww;

            const f2a o01 = *(const f2a*)(obs + pix * 3);
            const float o2 = obs[pix * 3 + 2];
            const f2a u01 = *(const f2a*)(u_k + pix * 3);
            const float u2 = u_k[pix * 3 + 2];
            const float ov[3] = {o01.x, o01.y, o2};
            const float us[3] = {u01.x, u01.y, u2};

            // w_k slice: 27 floats as 6x float4 + float2 + float
            const float* wkp = &w_k[(size_t)pix * 27];
            float wreg[27];
            {
                const f4a* v4 = (const f4a*)wkp;
                const f4a a0 = v4[0], a1 = v4[1], a2 = v4[2], a3 = v4[3], a4 = v4[4], a5 = v4[5];
                const f2a a6 = *(const f2a*)(wkp + 24);
                const float a7 = wkp[26];
                wreg[0] = a0.x;  wreg[1] = a0.y;  wreg[2] = a0.z;  wreg[3] = a0.w;
                wreg[4] = a1.x;  wreg[5] = a1.y;  wreg[6] = a1.z;  wreg[7] = a1.w;
                wreg[8] = a2.x;  wreg[9] = a2.y;  wreg[10] = a2.z; wreg[11] = a2.w;
                wreg[12] = a3.x; wreg[13] = a3.y; wreg[14] = a3.z; wreg[15] = a3.w;
                wreg[16] = a4.x; wreg[17] = a4.y; wreg[18] = a4.z; wreg[19] = a4.w;
                wreg[20] = a5.x; wreg[21] = a5.y; wreg[22] = a5.z; wreg[23] = a5.w;
                wreg[24] = a6.x; wreg[25] = a6.y; wreg[26] = a7;
            }

            float b[3], Bu[3], bu = 0.0f;
#pragma unroll
            for (int s = 0; s < 3; ++s) {
                b[s] = Pm[0 * 3 + s] * ov[0] + Pm[1 * 3 + s] * ov[1] + Pm[2 * 3 + s] * ov[2];
                Bu[s] = b[s] * us[s];
                bu += Bu[s];
            }
            const float inv_bu = 1.0f / bu;
            float Z[3];
#pragma unroll
            for (int s = 0; s < 3; ++s) { Z[s] = Bu[s] * inv_bu; row[s] = Z[s]; }

#pragma unroll
            for (int i = 0; i < 3; ++i) {
#pragma unroll
                for (int j = 0; j < 3; ++j) {
                    const int ij = i * 3 + j;
                    float du[3], sdu = 0.0f;
#pragma unroll
                    for (int s = 0; s < 3; ++s) {
                        float d = b[s] * wreg[s * 9 + ij];
                        if (s == j) d += ov[i] * us[s];
                        du[s] = d;
                        sdu += d;
                    }
#pragma unroll
                    for (int s = 0; s < 3; ++s)
                        row[(1 + ij) * 3 + s] = (du[s] - sdu * Z[s]) * inv_bu;
                }
            }
        }
    }

    // conv weights/bias (wave-uniform loads -> SGPRs)
    float cw[81];
#pragma unroll
    for (int i = 0; i < 81; ++i) cw[i] = conv_w[i];
    const float cb[3] = {conv_b[0], conv_b[1], conv_b[2]};

    __syncthreads();

    // ---------- Stage B: 2 threads per interior pixel (wave-uniform halves)
    const int half = tid >> 7;        // waves 0,1 -> half 0 ; waves 2,3 -> half 1
    const int pxl = tid & 127;
    const int tx = pxl & 15, ty = pxl >> 4;
    const int hp = (ty + 1) * HW_ + (tx + 1);
    const int pix = (h0 + ty) * IMW + (w0 + tx);

    // group 0: y = conv(Z)+b -> softmax  (both halves compute; avoids handoff)
    float p0, p1, p2;
    {
        float y[3] = {cb[0], cb[1], cb[2]};
#pragma unroll
        for (int ky = 0; ky < 3; ++ky) {
#pragma unroll
            for (int kx = 0; kx < 3; ++kx) {
                const float* nb = &lds[(hp + (ky - 1) * HW_ + (kx - 1)) * ROW];
                const float v0 = nb[0], v1 = nb[1], v2 = nb[2];
#pragma unroll
                for (int s = 0; s < 3; ++s)
                    y[s] += cw[s * 27 + 0 * 9 + ky * 3 + kx] * v0 +
                            cw[s * 27 + 1 * 9 + ky * 3 + kx] * v1 +
                            cw[s * 27 + 2 * 9 + ky * 3 + kx] * v2;
            }
        }
        const float m = fmaxf(y[0], fmaxf(y[1], y[2]));
        const float e0 = __expf(y[0] - m), e1 = __expf(y[1] - m), e2 = __expf(y[2] - m);
        const float inv = 1.0f / (e0 + e1 + e2);
        p0 = e0 * inv; p1 = e1 * inv; p2 = e2 * inv;
        if (half == 0) { out[pix * 3 + 0] = p0; out[pix * 3 + 1] = p1; out[pix * 3 + 2] = p2; }
    }

    // half 0: JVP groups ij=0..3 ; half 1: ij=4..8
    const int ij0 = half ? 4 : 0;
    const int ng  = half ? 5 : 4;
    float wout[5][3];
#pragma unroll
    for (int k = 0; k < 5; ++k) {
        if (k >= ng) break;
        const int g = ij0 + k + 1;            // LDS channel group index (1..9)
        float a[3] = {0.0f, 0.0f, 0.0f};
#pragma unroll
        for (int ky = 0; ky < 3; ++ky) {
#pragma unroll
            for (int kx = 0; kx < 3; ++kx) {
                const float* nb = &lds[(hp + (ky - 1) * HW_ + (kx - 1)) * ROW];
                const float v0 = nb[g * 3 + 0], v1 = nb[g * 3 + 1], v2 = nb[g * 3 + 2];
#pragma unroll
                for (int s = 0; s < 3; ++s)
                    a[s] += cw[s * 27 + 0 * 9 + ky * 3 + kx] * v0 +
                            cw[s * 27 + 1 * 9 + ky * 3 + kx] * v1 +
                            cw[s * 27 + 2 * 9 + ky * 3 + kx] * v2;
            }
        }
        const float dot = p0 * a[0] + p1 * a[1] + p2 * a[2];
        wout[k][0] = p0 * (a[0] - dot);
        wout[k][1] = p1 * (a[1] - dot);
        wout[k][2] = p2 * (a[2] - dot);
    }

    __syncthreads();   // all halo reads done; LDS can be reused

    // stage w-output in LDS (slot = pxl*27 + s*9 + ij) so stores are coalesced
#pragma unroll
    for (int k = 0; k < 5; ++k) {
        if (k >= ng) break;
        const int ij = ij0 + k;
#pragma unroll
        for (int s = 0; s < 3; ++s) lds[pxl * 27 + s * 9 + ij] = wout[k][s];
    }
    __syncthreads();

    // drain: 128 px * 27 ch = 3456 floats = 864 float4; 108 f4 per tile row
    const f4* lds4 = (const f4*)lds;
    float* outw = out + IMH * IMW * 3;
    for (int idx = tid; idx < NPIX * 27 / 4; idx += 256) {
        const int r = idx / 108;
        const int rem = idx - r * 108;
        *(f4*)(&outw[(h0 + r) * (IMW * 27) + w0 * 27 + rem * 4]) = lds4[idx];
    }
}

extern "C" void kernel_launch(void* const* d_in, const int* in_sizes, int n_in,
                              void* d_out, int out_size, void* d_ws, size_t ws_size,
                              hipStream_t stream) {
    const float* obs    = (const float*)d_in[0];
    const float* P      = (const float*)d_in[1];
    const float* u_k    = (const float*)d_in[2];
    const float* w_k    = (const float*)d_in[3];
    const float* conv_w = (const float*)d_in[4];
    const float* conv_b = (const float*)d_in[5];
    float* out = (float*)d_out;

    dim3 grid(IMW / TW, IMH / TH);   // (32, 64) = 2048 blocks
    hmm_fused<<<grid, 256, 0, stream>>>(obs, P, u_k, w_k, conv_w, conv_b, out);
}

// Round 6
// 106.554 us; speedup vs baseline: 1.3694x; 1.3694x over previous
//
#include <hip/hip_runtime.h>

#define IMH 512
#define IMW 512
#define TW 16
#define TH 8
#define HW_ (TW + 2)          // 18
#define HH_ (TH + 2)          // 10
#define NHALO (HW_ * HH_)     // 180
#define NPIX (TW * TH)        // 128 interior pixels per block
#define ROW 31                // padded floats per halo pixel (30 ch + 1 pad; gcd(31,32)=1)

typedef float f4 __attribute__((ext_vector_type(4)));
typedef float f4a __attribute__((ext_vector_type(4), aligned(4)));
typedef float f2a __attribute__((ext_vector_type(2), aligned(4)));

// R6 = R5 (2 threads/px for occupancy: grid 2048 blocks, ~24 waves/CU) with
// the spill bug removed: R5's launch_bounds(256,6) forced VGPR=40 + ~180MB of
// scratch traffic (FETCH 84MB / WRITE 152MB) — that, not the structure, was
// the 68us. Now launch_bounds(256,4) (cap 128; natural alloc ~80 = 6 w/SIMD)
// and the per-half JVP loops are fully static (two wave-uniform branches,
// compile-time indices, no runtime-bounded array loop -> no dynamic indexing,
// no spill). half 0: group-0 conv/softmax + u-store + JVP ij=0..3;
// half 1: group-0 conv/softmax (recompute, cheaper than handoff) + ij=4..8.
__global__ __launch_bounds__(256, 4)
void hmm_fused(const float* __restrict__ obs,
               const float* __restrict__ P,      // (S,O) indexed P[o*3+s] per einsum 'os,hwo->hws'
               const float* __restrict__ u_k,
               const float* __restrict__ w_k,    // (H,W,S,1,S,O) -> pix*27 + s*9 + i*3 + j
               const float* __restrict__ conv_w, // (S_out,S_in,3,3)
               const float* __restrict__ conv_b, // (S,)
               float* __restrict__ out) {        // [0, 512*512*3): u_kp1 ; rest: w_kp1_O
    __shared__ __align__(16) float lds[NHALO * ROW];   // 22,320 B

    const int tid = threadIdx.x;
    const int w0 = blockIdx.x * TW;
    const int h0 = blockIdx.y * TH;

    // P into registers (wave-uniform -> SGPRs)
    float Pm[9];
#pragma unroll
    for (int i = 0; i < 9; ++i) Pm[i] = P[i];

    // ---------- Stage A: halo pixels -> Z (ch 0..2) and w_pre (ch 3..29) in LDS
    if (tid < NHALO) {
        const int p = tid;
        const int hh = h0 + p / HW_ - 1;
        const int ww = w0 + p % HW_ - 1;
        float* row = &lds[p * ROW];
        if (hh < 0 || hh >= IMH || ww < 0 || ww >= IMW) {
#pragma unroll
            for (int c = 0; c < 30; ++c) row[c] = 0.0f;   // SAME zero padding
        } else {
            const int pix = hh * IMW + ww;

            const f2a o01 = *(const f2a*)(obs + pix * 3);
            const float o2 = obs[pix * 3 + 2];
            const f2a u01 = *(const f2a*)(u_k + pix * 3);
            const float u2 = u_k[pix * 3 + 2];
            const float ov[3] = {o01.x, o01.y, o2};
            const float us[3] = {u01.x, u01.y, u2};

            // w_k slice: 27 floats as 6x float4 + float2 + float
            const float* wkp = &w_k[(size_t)pix * 27];
            float wreg[27];
            {
                const f4a* v4 = (const f4a*)wkp;
                const f4a a0 = v4[0], a1 = v4[1], a2 = v4[2], a3 = v4[3], a4 = v4[4], a5 = v4[5];
                const f2a a6 = *(const f2a*)(wkp + 24);
                const float a7 = wkp[26];
                wreg[0] = a0.x;  wreg[1] = a0.y;  wreg[2] = a0.z;  wreg[3] = a0.w;
                wreg[4] = a1.x;  wreg[5] = a1.y;  wreg[6] = a1.z;  wreg[7] = a1.w;
                wreg[8] = a2.x;  wreg[9] = a2.y;  wreg[10] = a2.z; wreg[11] = a2.w;
                wreg[12] = a3.x; wreg[13] = a3.y; wreg[14] = a3.z; wreg[15] = a3.w;
                wreg[16] = a4.x; wreg[17] = a4.y; wreg[18] = a4.z; wreg[19] = a4.w;
                wreg[20] = a5.x; wreg[21] = a5.y; wreg[22] = a5.z; wreg[23] = a5.w;
                wreg[24] = a6.x; wreg[25] = a6.y; wreg[26] = a7;
            }

            float b[3], Bu[3], bu = 0.0f;
#pragma unroll
            for (int s = 0; s < 3; ++s) {
                b[s] = Pm[0 * 3 + s] * ov[0] + Pm[1 * 3 + s] * ov[1] + Pm[2 * 3 + s] * ov[2];
                Bu[s] = b[s] * us[s];
                bu += Bu[s];
            }
            const float inv_bu = 1.0f / bu;
            float Z[3];
#pragma unroll
            for (int s = 0; s < 3; ++s) { Z[s] = Bu[s] * inv_bu; row[s] = Z[s]; }

#pragma unroll
            for (int i = 0; i < 3; ++i) {
#pragma unroll
                for (int j = 0; j < 3; ++j) {
                    const int ij = i * 3 + j;
                    float du[3], sdu = 0.0f;
#pragma unroll
                    for (int s = 0; s < 3; ++s) {
                        float d = b[s] * wreg[s * 9 + ij];
                        if (s == j) d += ov[i] * us[s];
                        du[s] = d;
                        sdu += d;
                    }
#pragma unroll
                    for (int s = 0; s < 3; ++s)
                        row[(1 + ij) * 3 + s] = (du[s] - sdu * Z[s]) * inv_bu;
                }
            }
        }
    }

    // conv weights/bias (wave-uniform loads -> SGPRs)
    float cw[81];
#pragma unroll
    for (int i = 0; i < 81; ++i) cw[i] = conv_w[i];
    const float cb[3] = {conv_b[0], conv_b[1], conv_b[2]};

    __syncthreads();

    // ---------- Stage B: 2 threads per interior pixel (wave-uniform halves)
    const int half = tid >> 7;        // waves 0,1 -> half 0 ; waves 2,3 -> half 1
    const int pxl = tid & 127;
    const int tx = pxl & 15, ty = pxl >> 4;
    const int hp = (ty + 1) * HW_ + (tx + 1);
    const int pix = (h0 + ty) * IMW + (w0 + tx);

    // group 0: y = conv(Z)+b -> softmax  (both halves compute; avoids handoff)
    float p0, p1, p2;
    {
        float y[3] = {cb[0], cb[1], cb[2]};
#pragma unroll
        for (int ky = 0; ky < 3; ++ky) {
#pragma unroll
            for (int kx = 0; kx < 3; ++kx) {
                const float* nb = &lds[(hp + (ky - 1) * HW_ + (kx - 1)) * ROW];
                const float v0 = nb[0], v1 = nb[1], v2 = nb[2];
#pragma unroll
                for (int s = 0; s < 3; ++s)
                    y[s] += cw[s * 27 + 0 * 9 + ky * 3 + kx] * v0 +
                            cw[s * 27 + 1 * 9 + ky * 3 + kx] * v1 +
                            cw[s * 27 + 2 * 9 + ky * 3 + kx] * v2;
            }
        }
        const float m = fmaxf(y[0], fmaxf(y[1], y[2]));
        const float e0 = __expf(y[0] - m), e1 = __expf(y[1] - m), e2 = __expf(y[2] - m);
        const float inv = 1.0f / (e0 + e1 + e2);
        p0 = e0 * inv; p1 = e1 * inv; p2 = e2 * inv;
    }

    // JVP groups, fully static per half. wA holds up to 5 groups x 3 states.
    float wA[15];
#define CONV_GROUP(G, OUTK)                                                          \
    {                                                                                \
        float a0_ = 0.0f, a1_ = 0.0f, a2_ = 0.0f;                                    \
        _Pragma("unroll")                                                            \
        for (int ky = 0; ky < 3; ++ky) {                                             \
            _Pragma("unroll")                                                        \
            for (int kx = 0; kx < 3; ++kx) {                                         \
                const float* nb = &lds[(hp + (ky - 1) * HW_ + (kx - 1)) * ROW];      \
                const float v0 = nb[(G) * 3 + 0], v1 = nb[(G) * 3 + 1],              \
                            v2 = nb[(G) * 3 + 2];                                    \
                a0_ += cw[0 * 27 + 0 + ky * 3 + kx] * v0 +                           \
                       cw[0 * 27 + 9 + ky * 3 + kx] * v1 +                           \
                       cw[0 * 27 + 18 + ky * 3 + kx] * v2;                           \
                a1_ += cw[1 * 27 + 0 + ky * 3 + kx] * v0 +                           \
                       cw[1 * 27 + 9 + ky * 3 + kx] * v1 +                           \
                       cw[1 * 27 + 18 + ky * 3 + kx] * v2;                           \
                a2_ += cw[2 * 27 + 0 + ky * 3 + kx] * v0 +                           \
                       cw[2 * 27 + 9 + ky * 3 + kx] * v1 +                           \
                       cw[2 * 27 + 18 + ky * 3 + kx] * v2;                           \
            }                                                                        \
        }                                                                            \
        const float dot_ = p0 * a0_ + p1 * a1_ + p2 * a2_;                           \
        wA[(OUTK) * 3 + 0] = p0 * (a0_ - dot_);                                      \
        wA[(OUTK) * 3 + 1] = p1 * (a1_ - dot_);                                      \
        wA[(OUTK) * 3 + 2] = p2 * (a2_ - dot_);                                      \
    }

    if (half == 0) {
        out[pix * 3 + 0] = p0; out[pix * 3 + 1] = p1; out[pix * 3 + 2] = p2;
        CONV_GROUP(1, 0) CONV_GROUP(2, 1) CONV_GROUP(3, 2) CONV_GROUP(4, 3)
        wA[12] = 0.0f; wA[13] = 0.0f; wA[14] = 0.0f;
    } else {
        CONV_GROUP(5, 0) CONV_GROUP(6, 1) CONV_GROUP(7, 2) CONV_GROUP(8, 3) CONV_GROUP(9, 4)
    }
#undef CONV_GROUP

    __syncthreads();   // all halo reads done; LDS can be reused

    // stage w-output in LDS (slot = pxl*27 + s*9 + ij); stride 27 -> 2/bank, free
    if (half == 0) {
#pragma unroll
        for (int k = 0; k < 4; ++k)
#pragma unroll
            for (int s = 0; s < 3; ++s) lds[pxl * 27 + s * 9 + k] = wA[k * 3 + s];
    } else {
#pragma unroll
        for (int k = 0; k < 5; ++k)
#pragma unroll
            for (int s = 0; s < 3; ++s) lds[pxl * 27 + s * 9 + (4 + k)] = wA[k * 3 + s];
    }
    __syncthreads();

    // drain: 128 px * 27 ch = 3456 floats = 864 float4; 108 f4 per tile row
    const f4* lds4 = (const f4*)lds;
    float* outw = out + IMH * IMW * 3;
    for (int idx = tid; idx < NPIX * 27 / 4; idx += 256) {
        const int r = idx / 108;
        const int rem = idx - r * 108;
        *(f4*)(&outw[(h0 + r) * (IMW * 27) + w0 * 27 + rem * 4]) = lds4[idx];
    }
}

extern "C" void kernel_launch(void* const* d_in, const int* in_sizes, int n_in,
                              void* d_out, int out_size, void* d_ws, size_t ws_size,
                              hipStream_t stream) {
    const float* obs    = (const float*)d_in[0];
    const float* P      = (const float*)d_in[1];
    const float* u_k    = (const float*)d_in[2];
    const float* w_k    = (const float*)d_in[3];
    const float* conv_w = (const float*)d_in[4];
    const float* conv_b = (const float*)d_in[5];
    float* out = (float*)d_out;

    dim3 grid(IMW / TW, IMH / TH);   // (32, 64) = 2048 blocks
    hmm_fused<<<grid, 256, 0, stream>>>(obs, P, u_k, w_k, conv_w, conv_b, out);
}